// Round 15
// baseline (93.923 us; speedup 1.0000x reference)
//
#include <hip/hip_runtime.h>

// x: (2,8,256,256) fp32, F: 3x3 fp32.
#define HS 256
#define WSZ 256
#define NPIX (HS * WSZ)        // 65536 pixels
#define NCH 16                 // B*C
#define NELEM (NPIX * NCH)

typedef float f4 __attribute__((ext_vector_type(4)));

// ---------------------------------------------------------------------------
// Transpose (bc, h, w) -> (h, w, bc), LDS-tiled, coalesced both sides.
// Also zeroes a 512 B pad at T[NELEM..NELEM+128) — the invalid-sample target
// (wide enough for any immediate-offset load). Rebuilt every launch.
// ---------------------------------------------------------------------------
__global__ __launch_bounds__(256) void transpose_kernel(const float* __restrict__ x,
                                                        float* __restrict__ T) {
    __shared__ float lds[16][257];   // +1 pad
    int tid  = threadIdx.x;
    int base = blockIdx.x * 256;
#pragma unroll
    for (int ch = 0; ch < 16; ++ch)
        lds[ch][tid] = x[ch * NPIX + base + tid];   // coalesced 1KB per instr
    if (blockIdx.x == 0 && tid < 128) T[NELEM + tid] = 0.0f;  // zero pad
    __syncthreads();
    float4* T4 = (float4*)T;
#pragma unroll
    for (int it = 0; it < 4; ++it) {
        int idx = it * 256 + tid;    // 0..1023 float4s of this tile
        int p   = idx >> 2;          // local pixel
        int q   = idx & 3;           // channel quad
        float4 o;
        o.x = lds[q * 4 + 0][p];
        o.y = lds[q * 4 + 1][p];
        o.z = lds[q * 4 + 2][p];
        o.w = lds[q * 4 + 3][p];
        T4[base * 4 + idx] = o;      // contiguous 16B/lane -> coalesced
    }
}

// ---------------------------------------------------------------------------
// Geometry (bit-exact, verified R6): FMA-contracted einsum, f32.
// ---------------------------------------------------------------------------
struct LineGeom {
    float p, q, c;
    bool  col;
};

__device__ __forceinline__ LineGeom make_geom(const float* __restrict__ F, int pix) {
#pragma clang fp contract(off)
    int w = pix & (WSZ - 1);
    int h = pix >> 8;
    float u = (float)w, v = (float)h;
    float a = __builtin_fmaf(F[3], v, F[0] * u) + F[6];
    float b = __builtin_fmaf(F[4], v, F[1] * u) + F[7];
    float c = __builtin_fmaf(F[5], v, F[2] * u) + F[8];
    const float eps = 1e-8f;
    float bs = (fabsf(b) < eps) ? eps : b;
    float as = (fabsf(a) < eps) ? eps : a;
    LineGeom g;
    g.col = (fabsf(b) >= fabsf(a));
    g.p   = g.col ? a : b;
    g.q   = g.col ? bs : as;
    g.c   = c;
    return g;
}

// Chain (bit-exact, verified R6): t = fma(p,s,c); y = (-t)/q IEEE f32; rint.
// Returns the RAW rounded integer; validity tested as (unsigned)y < 256u.
__device__ __forceinline__ int chainY(const LineGeom& g, int s) {
#pragma clang fp contract(off)
    float t  = __builtin_fmaf(g.p, (float)s, g.c);
    float y  = (-t) / g.q;
    return (int)__builtin_rintf(y);
}

// ---------------------------------------------------------------------------
// Gather: 32 threads/pixel = quad(4) x s-eighth(8), 32 samples per thread.
// Thread computes s%4==quad chains of its eighth, DPP-broadcasts the row to
// its quad group; col-specialized addressing: float4 index = (y<<10)|(s<<2)|
// quad with the per-j step (+4 f4/sample) folded into the load's immediate
// offset; invalid rows redirect into the 512 B zero pad. 8-deep load batches.
// ---------------------------------------------------------------------------
#define QUAD_BCAST(dst, src, ctrl)                                              \
    dst = __builtin_amdgcn_mov_dpp(src, ctrl, 0xf, 0xf, false)

__global__ __launch_bounds__(256, 8) void epi_gather(const f4* __restrict__ T4,
                                                     const float* __restrict__ x,
                                                     const float* __restrict__ F,
                                                     float* __restrict__ out) {
    int tid  = blockIdx.x * 256 + threadIdx.x;
    int quad = tid & 3;
    int sq   = (tid >> 2) & 7;           // s-eighth
    int pix  = tid >> 5;

    LineGeom g = make_geom(F, pix);
    f4 acc = {0.f, 0.f, 0.f, 0.f};

    if (g.col) {
        const int zeroF4 = NPIX * 4 + quad;  // start of zero pad (512 B = 32 f4)
        int schain = (sq << 5) + quad;       // s of my chains: sq*32 + quad + 4k
        int sPart  = ((sq << 5) << 2) | quad;  // (s<<2)|quad for j=0 of batch

#pragma unroll
        for (int m = 0; m < 4; ++m) {
            int t0 = chainY(g, schain); schain += 4;
            int t1 = chainY(g, schain); schain += 4;
            int fb[8];
            int tj;
            // fb[j] excludes the per-sample +4*J f4-step; that folds into the
            // load's immediate offset (zero redirect compensates).
#define IDX(J, SRC, CTRL)                                                       \
            QUAD_BCAST(tj, SRC, CTRL);                                          \
            fb[J] = (tj << 10) | sPart;                                         \
            fb[J] = ((unsigned)tj < 256u) ? fb[J] : (zeroF4 - 4 * (J));
            IDX(0, t0, 0x00) IDX(1, t0, 0x55) IDX(2, t0, 0xAA) IDX(3, t0, 0xFF)
            IDX(4, t1, 0x00) IDX(5, t1, 0x55) IDX(6, t1, 0xAA) IDX(7, t1, 0xFF)
#undef IDX
            // batch-issue 8 independent 16B loads, +4*J folded as imm offset
            f4 v0 = T4[fb[0] +  0], v1 = T4[fb[1] +  4];
            f4 v2 = T4[fb[2] +  8], v3 = T4[fb[3] + 12];
            f4 v4 = T4[fb[4] + 16], v5 = T4[fb[5] + 20];
            f4 v6 = T4[fb[6] + 24], v7 = T4[fb[7] + 28];
            // ascending-s accumulate (vector adds -> v_pk_add_f32)
            acc += v0; acc += v1; acc += v2; acc += v3;
            acc += v4; acc += v5; acc += v6; acc += v7;
            sPart += 32;                     // 8 samples * 4 f4/sample
        }
    } else {
        // Row mode (never taken for this F; generic correctness): per-sample
        // scalar gathers from x over this thread's eighth.
        int lo = sq << 5;
        int ch = quad * 4;
        for (int s = lo; s < lo + 32; ++s) {
            int xi = chainY(g, s);
            if ((unsigned)xi < 256u) {
                int addr = s * WSZ + xi;
                acc.x += x[(ch + 0) * NPIX + addr];
                acc.y += x[(ch + 1) * NPIX + addr];
                acc.z += x[(ch + 2) * NPIX + addr];
                acc.w += x[(ch + 3) * NPIX + addr];
            }
        }
    }

    // merge the eight s-eighths (sq = lane bits 2..4): xor16, xor8, xor4
    acc.x += __shfl_xor(acc.x, 16, 64);
    acc.y += __shfl_xor(acc.y, 16, 64);
    acc.z += __shfl_xor(acc.z, 16, 64);
    acc.w += __shfl_xor(acc.w, 16, 64);
    acc.x += __shfl_xor(acc.x, 8, 64);
    acc.y += __shfl_xor(acc.y, 8, 64);
    acc.z += __shfl_xor(acc.z, 8, 64);
    acc.w += __shfl_xor(acc.w, 8, 64);
    acc.x += __shfl_xor(acc.x, 4, 64);
    acc.y += __shfl_xor(acc.y, 4, 64);
    acc.z += __shfl_xor(acc.z, 4, 64);
    acc.w += __shfl_xor(acc.w, 4, 64);

    if (sq == 0) {
        int ch = quad * 4;
        out[(ch + 0) * NPIX + pix] = acc.x;
        out[(ch + 1) * NPIX + pix] = acc.y;
        out[(ch + 2) * NPIX + pix] = acc.z;
        out[(ch + 3) * NPIX + pix] = acc.w;
    }
}

// ---------------------------------------------------------------------------
// Fallback without workspace: direct per-sample gathers from (bc,h,w).
// ---------------------------------------------------------------------------
__global__ __launch_bounds__(256) void epi_gather_direct(const float* __restrict__ x,
                                                         const float* __restrict__ F,
                                                         float* __restrict__ out) {
    int tid  = blockIdx.x * 256 + threadIdx.x;
    int quad = tid & 3;
    int pix  = tid >> 2;

    LineGeom g = make_geom(F, pix);

    float4 acc = make_float4(0.f, 0.f, 0.f, 0.f);
    int base = quad * 4;

#pragma unroll 2
    for (int s = 0; s < 256; ++s) {
        int  yi    = chainY(g, s);
        bool valid = ((unsigned)yi < 256u);
        int  tcl   = valid ? yi : 0;
        int  addr  = g.col ? (tcl * WSZ + s) : (s * WSZ + tcl);
        if (valid) {
            acc.x += x[(base + 0) * NPIX + addr];
            acc.y += x[(base + 1) * NPIX + addr];
            acc.z += x[(base + 2) * NPIX + addr];
            acc.w += x[(base + 3) * NPIX + addr];
        }
    }

    out[(base + 0) * NPIX + pix] = acc.x;
    out[(base + 1) * NPIX + pix] = acc.y;
    out[(base + 2) * NPIX + pix] = acc.z;
    out[(base + 3) * NPIX + pix] = acc.w;
}

extern "C" void kernel_launch(void* const* d_in, const int* in_sizes, int n_in,
                              void* d_out, int out_size, void* d_ws, size_t ws_size,
                              hipStream_t stream) {
    const float* x   = (const float*)d_in[0];
    const float* F   = (const float*)d_in[1];
    float*       out = (float*)d_out;

    const size_t need = (size_t)(NELEM + 128) * sizeof(float);
    if (ws_size >= need) {
        float* T = (float*)d_ws;
        transpose_kernel<<<NPIX / 256, 256, 0, stream>>>(x, T);
        epi_gather<<<(NPIX * 32) / 256, 256, 0, stream>>>((const f4*)T, x, F, out);
    } else {
        epi_gather_direct<<<(NPIX * 4) / 256, 256, 0, stream>>>(x, F, out);
    }
}